// Round 8
// baseline (465.265 us; speedup 1.0000x reference)
//
#include <hip/hip_runtime.h>
#include <cstdint>

// ---------------------------------------------------------------------------
// MultiHeadAttention (B=8,S=1024,D=1024,H=16,E=64). Inputs fp32, output fp32.
// Quirks: scale = 1/sqrt(8) (d_k = batch quirk); tril + exact-zero -> -1e9
// (fp32, pre-round); softmax over HEADS axis (local per (b,q,k)).
//
// R15: triangle + balance + co-residency from PROVEN parts only.
//  Evidence: R14 = 172us, all pipes <21% busy at 1 block/CU (lockstep floor
//  ~10.8us/KVBLK64-iter). Triangle halves work (k>q => all heads masked =>
//  attn==1/16 exact, R8-R11-proven); atomic-P merge + suffix tail proven
//  (R10/R11). Past failures: forced launch-bounds (spills R8/R10/R12),
//  runtime loop shapes (R11 2x/iter). R15 dodges both:
//   - R14 body byte-for-byte, static 8-trip loop + block-uniform skip
//     (if t<myCnt), no forced occupancy caps (launch_bounds(1024,4)).
//   - grid 512: (b, qt, half) front/back half-triangle blocks, heavy-first
//     rank order -> per-XCD 64-blocks/32-CUs packs ~balanced (~10.4 units
//     vs 16 now).
//   - IN-PLACE softmax: scores+attn share one 72KB LDS buffer (each (q,k)
//     u32 owned by exactly 1 thread -> hazard-free); +3rd barrier (R13:
//     barrier count is free). 72KB + VGPR~64 -> 2 blocks/CU possible.
//   - tail (suffix-sum(V) * 1/16) on back-half block; exactly 2 atomic
//     contributors per element -> deterministic.
// ---------------------------------------------------------------------------

typedef unsigned short u16;
typedef unsigned int   u32;
typedef __attribute__((ext_vector_type(8))) __bf16         bf16x8;
typedef __attribute__((ext_vector_type(8))) unsigned short ushort8;
typedef __attribute__((ext_vector_type(4))) float          f32x4;

#define S_ 1024
#define D_ 1024
#define H_ 16
#define E_ 64

__device__ __forceinline__ float b2f(u16 h) {
  union { u32 u; float f; } v; v.u = ((u32)h) << 16; return v.f;
}
__device__ __forceinline__ u16 f2b(float f) {      // round-to-nearest-even
  union { float f; u32 u; } v; v.f = f;
  u32 r = v.u + 0x7fffu + ((v.u >> 16) & 1u);
  return (u16)(r >> 16);
}

typedef const __attribute__((address_space(1))) u32 gu32;
typedef       __attribute__((address_space(3))) u32 lu32;

// 16B global->LDS direct load; LDS dest must be wave-uniform base + lane*16.
__device__ __forceinline__ void gload_lds16(const u16* g, u16* l) {
  __builtin_amdgcn_global_load_lds((gu32*)(uintptr_t)g, (lu32*)(uintptr_t)l,
                                   16, 0, 0);
}

// ---------------------------------------------------------------------------
// fp32 -> bf16 elementwise convert (n = multiple of 2048).
// ---------------------------------------------------------------------------
__global__ __launch_bounds__(256, 1) void cvt_bf16(
    const float* __restrict__ src, u16* __restrict__ dst)
{
  const size_t i = (size_t)blockIdx.x * 256 + threadIdx.x;
  float4 a = ((const float4*)src)[2 * i];
  float4 b = ((const float4*)src)[2 * i + 1];
  ushort8 o;
  o[0] = f2b(a.x); o[1] = f2b(a.y); o[2] = f2b(a.z); o[3] = f2b(a.w);
  o[4] = f2b(b.x); o[5] = f2b(b.y); o[6] = f2b(b.z); o[7] = f2b(b.w);
  ((ushort8*)dst)[i] = o;
}

// ---------------------------------------------------------------------------
// Weight transpose+convert: W fp32 [K][N] -> Wt bf16 [N][K]. 64x64 tiles.
// ---------------------------------------------------------------------------
__global__ __launch_bounds__(256, 1) void trans_cvt_w(
    const float* __restrict__ W, u16* __restrict__ Wt)
{
  __shared__ u16 t[64][72];
  const int k0 = blockIdx.x * 64, n0 = blockIdx.y * 64;
  const int row = threadIdx.x >> 3;
  const int cs  = (threadIdx.x & 7) * 8;
#pragma unroll
  for (int p = 0; p < 2; ++p) {
    int r = row + p * 32;
    const float* Wp = W + (size_t)(k0 + r) * 1024 + n0 + cs;
    float4 a = *(const float4*)(Wp);
    float4 b = *(const float4*)(Wp + 4);
    u16* tp = &t[r][cs];
    tp[0] = f2b(a.x); tp[1] = f2b(a.y); tp[2] = f2b(a.z); tp[3] = f2b(a.w);
    tp[4] = f2b(b.x); tp[5] = f2b(b.y); tp[6] = f2b(b.z); tp[7] = f2b(b.w);
  }
  __syncthreads();
#pragma unroll
  for (int p = 0; p < 2; ++p) {
    int n = row + p * 32;
    ushort8 v;
#pragma unroll
    for (int i = 0; i < 8; ++i) v[i] = t[cs + i][n];
    *(ushort8*)(Wt + (size_t)(n0 + n) * 1024 + k0 + cs) = v;
  }
}

// ---------------------------------------------------------------------------
// bf16 MFMA GEMM: C[M][N] = A[M][K] @ Bt[N][K]^T + bias[N] (fp32 accum).
// 128x128 tile, BK=32, 256 threads / 4 waves. m97-style global_load_lds
// width-16 staging. out_f32: 1 -> fp32 stores, 0 -> bf16 stores.
// ---------------------------------------------------------------------------
__global__ __launch_bounds__(256, 1) void gemm_bf16(
    const u16* __restrict__ A, const u16* __restrict__ Bt,
    const float* __restrict__ bias, void* __restrict__ Cv,
    int M, int N, int K, int out_f32)
{
  __shared__ u16 As[128 * 32];   // [m][k] row-major, 8KB
  __shared__ u16 Bs[128 * 32];   // [n][k] row-major, 8KB
  const int tid  = threadIdx.x;
  const int wave = tid >> 6;
  const int lane = tid & 63;
  const int quad = lane >> 4;
  const int l16  = lane & 15;
  const int m0   = (wave & 1) * 64;
  const int n0   = (wave >> 1) * 64;

  const u16* Ab = A  + (size_t)blockIdx.x * 128 * K;
  const u16* Bb = Bt + (size_t)blockIdx.y * 128 * K;

  f32x4 acc[4][4];
#pragma unroll
  for (int i = 0; i < 4; ++i)
#pragma unroll
    for (int j = 0; j < 4; ++j) acc[i][j] = (f32x4){0.f, 0.f, 0.f, 0.f};

  for (int kb = 0; kb < K; kb += 32) {
    __syncthreads();               // prior iter's LDS reads done
#pragma unroll
    for (int p = 0; p < 2; ++p) {  // 512 16B segs over 256 threads
      int seg = tid + p * 256;     // = (wave*64+p*256) + lane -> base+lane*16
      int row = seg >> 2, ks = seg & 3;
      gload_lds16(Ab + (size_t)row * K + kb + ks * 8, As + seg * 8);
      gload_lds16(Bb + (size_t)row * K + kb + ks * 8, Bs + seg * 8);
    }
    __builtin_amdgcn_s_waitcnt(0); // drain vmcnt before barrier
    __syncthreads();

    bf16x8 af[4], bfr[4];
#pragma unroll
    for (int i = 0; i < 4; ++i)    // A-frag: m=lane&15, k=quad*8+j
      af[i] = *(const bf16x8*)(As + (m0 + i * 16 + l16) * 32 + quad * 8);
#pragma unroll
    for (int j = 0; j < 4; ++j)    // B-frag: n=lane&15, k=quad*8+j
      bfr[j] = *(const bf16x8*)(Bs + (n0 + j * 16 + l16) * 32 + quad * 8);
#pragma unroll
    for (int i = 0; i < 4; ++i)
#pragma unroll
      for (int j = 0; j < 4; ++j)
        acc[i][j] = __builtin_amdgcn_mfma_f32_16x16x32_bf16(
            af[i], bfr[j], acc[i][j], 0, 0, 0);
  }

  float bv[4];
#pragma unroll
  for (int j = 0; j < 4; ++j)
    bv[j] = bias[(size_t)blockIdx.y * 128 + n0 + j * 16 + l16];

  if (out_f32) {
    float* C = (float*)Cv;
#pragma unroll
    for (int i = 0; i < 4; ++i) {
      int r = blockIdx.x * 128 + m0 + i * 16 + quad * 4;   // row=quad*4+reg
#pragma unroll
      for (int j = 0; j < 4; ++j) {
        int c = blockIdx.y * 128 + n0 + j * 16 + l16;      // col=lane&15
#pragma unroll
        for (int reg = 0; reg < 4; ++reg)
          C[(size_t)(r + reg) * N + c] = acc[i][j][reg] + bv[j];
      }
    }
  } else {
    u16* C = (u16*)Cv;
#pragma unroll
    for (int i = 0; i < 4; ++i) {
      int r = blockIdx.x * 128 + m0 + i * 16 + quad * 4;
#pragma unroll
      for (int j = 0; j < 4; ++j) {
        int c = blockIdx.y * 128 + n0 + j * 16 + l16;
#pragma unroll
        for (int reg = 0; reg < 4; ++reg)
          C[(size_t)(r + reg) * N + c] = f2b(acc[i][j][reg] + bv[j]);
      }
    }
  }
}

// ---------------------------------------------------------------------------
// V transpose (bf16): V[b][s][h*64+e] -> Vt[(b*16+h)*64+e][s]  (per-head E,S)
// ---------------------------------------------------------------------------
__global__ __launch_bounds__(256, 1) void transpose_v(
    const u16* __restrict__ V, u16* __restrict__ Vt)
{
  __shared__ u16 t[64][72];
  const int s0 = blockIdx.x * 64;
  const int bh = blockIdx.y;           // b*16 + h
  const int b = bh >> 4, h = bh & 15;
  const int row = threadIdx.x >> 3;
  const int cs  = (threadIdx.x & 7) * 8;
#pragma unroll
  for (int p = 0; p < 2; ++p) {
    int s = row + p * 32;
    *(ushort8*)(&t[s][cs]) = *(const ushort8*)(
        V + ((size_t)(b * S_ + s0 + s)) * D_ + h * E_ + cs);
  }
  __syncthreads();
#pragma unroll
  for (int p = 0; p < 2; ++p) {
    int e = row + p * 32;
    ushort8 v;
#pragma unroll
    for (int i = 0; i < 8; ++i) v[i] = t[cs + i][e];
    *(ushort8*)(Vt + ((size_t)(bh * E_ + e)) * S_ + s0 + cs) = v;
  }
}

// ---------------------------------------------------------------------------
// Fused attention, softmax over HEADS, bf16 MFMA.  R15:
// grid 512 = (b=id&7, rank=id>>3 heavy-first): qt = 31-(rank>>1),
// half = rank&1. Block does its half of qt's triangle tiles (<=8, static
// 8-trip loop, uniform skip) + (half1) suffix tail. In-place softmax in one
// 72KB LDS buffer; 3 barriers/iter. Partials -> fp32 unsafeAtomicAdd into
// zeroed P (exactly 2 contributors/elem). R14 phase bodies verbatim.
// ---------------------------------------------------------------------------
__global__ __launch_bounds__(1024, 4) void attn_headsoftmax(
    const u16* __restrict__ Qg,   // [B][S][D] bf16
    const u16* __restrict__ Kg,   // [B][S][D] bf16
    const u16* __restrict__ Vt,   // [B*H][E][S] bf16
    float* __restrict__ P)        // [B][S][D] fp32, zeroed
{
  const int id   = blockIdx.x;         // 0..511; id&7 == b == XCD
  const int b    = id & 7;
  const int rk   = id >> 3;            // 0..63, heavy-first
  const int qt   = 31 - (rk >> 1);
  const int half = rk & 1;
  const int tid  = threadIdx.x;
  const int h    = tid >> 6;
  const int lane = tid & 63;
  const int quad = lane >> 4;
  const int l16  = lane & 15;
  const int q0   = qt * 32;

  const int nt    = (qt >> 1) + 1;       // KVBLK-64 tiles with unmasked cols
  const int c0    = (nt + 1) >> 1;       // ceil(nt/2) -> front half
  const int myLo  = half ? c0 : 0;
  const int myCnt = half ? (nt - c0) : c0;   // 0..8

  __shared__ u16 S[16][32][72];        // in-place scores -> attn (72KB)

  const u16* Kh = Kg + (size_t)b * S_ * D_ + h * E_;
  const u16* Vh = Vt + ((size_t)(b * H_ + h) * E_) * S_;

  // 1/sqrt(8), correctly rounded fp32; s==0 <=> dot==0 under both forms.
  const float inv_rsq8 = 0.35355339059327373f;

  // ---- Q fragments (R7 verbatim) ----
  bf16x8 qf[2][2];
  {
    const u16* Qb = Qg + ((size_t)(b * S_ + q0)) * D_ + h * E_;
#pragma unroll
    for (int i = 0; i < 2; ++i)
#pragma unroll
      for (int c = 0; c < 2; ++c)
        qf[i][c] = *(const bf16x8*)(Qb + (size_t)(i * 16 + l16) * D_ +
                                    c * 32 + quad * 8);
  }

  f32x4 oacc[2][4];
#pragma unroll
  for (int i = 0; i < 2; ++i)
#pragma unroll
    for (int nc = 0; nc < 4; ++nc) oacc[i][nc] = (f32x4){0.f, 0.f, 0.f, 0.f};

  // softmax thread mapping: (q = tid>>5, k-chunk = (tid&31)*2)
  const int sm_q  = tid >> 5;
  const int sm_k  = (tid & 31) * 2;

#pragma unroll 1
  for (int t = 0; t < 8; ++t) {
    if (t < myCnt) {                 // block-uniform -> cheap scalar skip
      const int kt = myLo + t;
      const int k0 = kt * 64;
      // ---- QK^T: two 32-col sub-tiles; skip uniformly-masked ones ----
#pragma unroll
      for (int c2 = 0; c2 < 2; ++c2) {
        const int ks0 = k0 + c2 * 32;
        if (ks0 <= q0 + 31) {        // else softmax writes 1/16 directly
          const u16* Kb = Kh + (size_t)ks0 * D_;
          bf16x8 kf[2][2];
#pragma unroll
          for (int nc = 0; nc < 2; ++nc)
#pragma unroll
            for (int c = 0; c < 2; ++c)
              kf[nc][c] = *(const bf16x8*)(Kb + (size_t)(nc * 16 + l16) * D_ +
                                           c * 32 + quad * 8);
          f32x4 sacc[2][2];
#pragma unroll
          for (int i = 0; i < 2; ++i)
#pragma unroll
            for (int nc = 0; nc < 2; ++nc)
              sacc[i][nc] = (f32x4){0.f, 0.f, 0.f, 0.f};
#pragma unroll
          for (int c = 0; c < 2; ++c)
#pragma unroll
            for (int i = 0; i < 2; ++i)
#pragma unroll
              for (int nc = 0; nc < 2; ++nc)
                sacc[i][nc] = __builtin_amdgcn_mfma_f32_16x16x32_bf16(
                    qf[i][c], kf[nc][c], sacc[i][nc], 0, 0, 0);
#pragma unroll
          for (int i = 0; i < 2; ++i)
#pragma unroll
            for (int nc = 0; nc < 2; ++nc)
#pragma unroll
              for (int reg = 0; reg < 4; ++reg) {
                int qrow = i * 16 + quad * 4 + reg;  // C: row=quad*4+reg
                int kcol = nc * 16 + l16;            // C: col=lane&15
                float s = sacc[i][nc][reg] * inv_rsq8;
                if ((ks0 + kcol > q0 + qrow) || (s == 0.0f)) s = -1e9f;
                S[h][qrow][c2 * 32 + kcol] = f2b(s);
              }
        }
      }
      __syncthreads();
      {  // ---- softmax across 16 heads; (q, 2 consec k) per thread,
         //      IN PLACE (each (q,k) u32 owned by exactly one thread) ----
        const int qpos = q0 + sm_q;
        const int kpos = k0 + sm_k;
        int nU = qpos - kpos + 1;          // unmasked count in chunk [0..2]
        nU = nU < 0 ? 0 : (nU > 2 ? 2 : nU);
        if (nU == 0) {
          const u32 cc = 0x3D803D80u;      // bf16(1/16) x2
#pragma unroll
          for (int hh = 0; hh < 16; ++hh)
            *(u32*)&S[hh][sm_q][sm_k] = cc;
        } else {
          u32 v2[16];
#pragma unroll
          for (int hh = 0; hh < 16; ++hh)
            v2[hh] = *(const u32*)&S[hh][sm_q][sm_k];
          u32 o2[16];
          {  // element 0 (always unmasked when nU>=1)
            float e0,e1,e2,e3,e4,e5,e6,e7,e8,e9,ea,eb,ec,ed,ee,ef;
            e0 = __expf(b2f((u16)(v2[0]  & 0xffffu)));
            e1 = __expf(b2f((u16)(v2[1]  & 0xffffu)));
            e2 = __expf(b2f((u16)(v2[2]  & 0xffffu)));
            e3 = __expf(b2f((u16)(v2[3]  & 0xffffu)));
            e4 = __expf(b2f((u16)(v2[4]  & 0xffffu)));
            e5 = __expf(b2f((u16)(v2[5]  & 0xffffu)));
            e6 = __expf(b2f((u16)(v2[6]  & 0xffffu)));
            e7 = __expf(b2f((u16)(v2[7]  & 0xffffu)));
            e8 = __expf(b2f((u16)(v2[8]  & 0xffffu)));
            e9 = __expf(b2f((u16)(v2[9]  & 0xffffu)));
            ea = __expf(b2f((u16)(v2[10] & 0xffffu)));
            eb = __expf(b2f((u16)(v2[11] & 0xffffu)));
            ec = __expf(b2f((u16)(v2[12] & 0xffffu)));
            ed = __expf(b2f((u16)(v2[13] & 0xffffu)));
            ee = __expf(b2f((u16)(v2[14] & 0xffffu)));
            ef = __expf(b2f((u16)(v2[15] & 0xffffu)));
            float sum = (((e0+e1)+(e2+e3))+((e4+e5)+(e6+e7)))
                      + (((e8+e9)+(ea+eb))+((ec+ed)+(ee+ef)));
            float inv = 1.0f / sum;
            bool z = (sum == 0.0f);        // all-quirk guard -> uniform 1/16
            o2[0]  = z ? 0x3D80u : (u32)f2b(e0 * inv);
            o2[1]  = z ? 0x3D80u : (u32)f2b(e1 * inv);
            o2[2]  = z ? 0x3D80u : (u32)f2b(e2 * inv);
            o2[3]  = z ? 0x3D80u : (u32)f2b(e3 * inv);
            o2[4]  = z ? 0x3D80u : (u32)f2b(e4 * inv);
            o2[5]  = z ? 0x3D80u : (u32)f2b(e5 * inv);
            o2[6]  = z ? 0x3D80u : (u32)f2b(e6 * inv);
            o2[7]  = z ? 0x3D80u : (u32)f2b(e7 * inv);
            o2[8]  = z ? 0x3D80u : (u32)f2b(e8 * inv);
            o2[9]  = z ? 0x3D80u : (u32)f2b(e9 * inv);
            o2[10] = z ? 0x3D80u : (u32)f2b(ea * inv);
            o2[11] = z ? 0x3D80u : (u32)f2b(eb * inv);
            o2[12] = z ? 0x3D80u : (u32)f2b(ec * inv);
            o2[13] = z ? 0x3D80u : (u32)f2b(ed * inv);
            o2[14] = z ? 0x3D80u : (u32)f2b(ee * inv);
            o2[15] = z ? 0x3D80u : (u32)f2b(ef * inv);
          }
          if (nU == 2) {  // element 1 real
            float e0,e1,e2,e3,e4,e5,e6,e7,e8,e9,ea,eb,ec,ed,ee,ef;
            e0 = __expf(b2f((u16)(v2[0]  >> 16)));
            e1 = __expf(b2f((u16)(v2[1]  >> 16)));
            e2 = __expf(b2f((u16)(v2[2]  >> 16)));
            e3 = __expf(b2f((u16)(v2[3]  >> 16)));
            e4 = __expf(b2f((u16)(v2[4]  >> 16)));
            e5 = __expf(b2f((u16)(v2[5]  >> 16)));
            e6 = __expf(b2f((u16)(v2[6]  >> 16)));
            e7 = __expf(b2f((u16)(v2[7]  >> 16)));
            e8 = __expf(b2f((u16)(v2[8]  >> 16)));
            e9 = __expf(b2f((u16)(v2[9]  >> 16)));
            ea = __expf(b2f((u16)(v2[10] >> 16)));
            eb = __expf(b2f((u16)(v2[11] >> 16)));
            ec = __expf(b2f((u16)(v2[12] >> 16)));
            ed = __expf(b2f((u16)(v2[13] >> 16)));
            ee = __expf(b2f((u16)(v2[14] >> 16)));
            ef = __expf(b2f((u16)(v2[15] >> 16)));
            float sum = (((e0+e1)+(e2+e3))+((e4+e5)+(e6+e7)))
                      + (((e8+e9)+(ea+eb))+((ec+ed)+(ee+ef)));
            float inv = 1.0f / sum;
            bool z = (sum == 0.0f);
            o2[0]  |= ((u32)(z ? 0x3D80u : f2b(e0 * inv))) << 16;
            o2[1]  |= ((u32)(z ? 0x3D80u : f2b(e1 * inv))) << 16;
            o2[2]  |= ((u32)(z ? 0x3D80u : f2b(e2 * inv))) << 16;
            o2[3]  |= ((u32)(z ? 0x3D80u : f2b(e3 * inv))) << 16;
            o2[4]  |= ((u32)(z ? 0x3D80u : f2b(e4 * inv))) << 16;
            o2[5]  |= ((u32)(z ? 0x3D80u : f2b(e5 * inv))) << 16;
            o2[6]  |= ((u32)(z ? 0x3D80u : f2b(e6 * inv))) << 16;
            o2[7]  |= ((u32)(z ? 0x3D80u : f2b(e7 * inv))) << 16;
            o2[8]  |= ((u32)(z ? 0x3D80u : f2b(e8 * inv))) << 16;
            o2[9]  |= ((u32)(z ? 0x3D80u : f2b(e9 * inv))) << 16;
            o2[10] |= ((u32)(z ? 0x3D80u : f2b(ea * inv))) << 16;
            o2[11] |= ((u32)(z ? 0x3D80u : f2b(eb * inv))) << 16;
            o2[12] |= ((u32)(z ? 0x3D80u : f2b(ec * inv))) << 16;
            o2[13] |= ((u32)(z ? 0x3D80u : f2b(ed * inv))) << 16;
            o2[14] |= ((u32)(z ? 0x3D80u : f2b(ee * inv))) << 16;
            o2[15] |= ((u32)(z ? 0x3D80u : f2b(ef * inv))) << 16;
          } else {        // element 1 masked -> 1/16
#pragma unroll
            for (int hh = 0; hh < 16; ++hh) o2[hh] |= 0x3D800000u;
          }
#pragma unroll
          for (int hh = 0; hh < 16; ++hh)
            *(u32*)&S[hh][sm_q][sm_k] = o2[hh];
        }
      }
      __syncthreads();
      // ---- PV: two 32-col sub-tiles (masked attn == 1/16, included) ----
#pragma unroll
      for (int c2 = 0; c2 < 2; ++c2) {
        bf16x8 af[2];
#pragma unroll
        for (int i = 0; i < 2; ++i)    // A: m=q (lane&15), k=s (quad*8+jj)
          af[i] = *(const bf16x8*)(&S[h][i * 16 + l16][c2 * 32 + quad * 8]);
        const u16* Vb = Vh + k0 + c2 * 32;
        bf16x8 vf[4];
#pragma unroll
        for (int nc = 0; nc < 4; ++nc) // B: n=e (lane&15), k=s (quad*8+jj)
          vf[nc] = *(const bf16x8*)(Vb + (size_t)(nc * 16 + l16) * S_ +
                                    quad * 8);
#pragma unroll
        for (int i = 0; i < 2; ++i)
#pragma unroll
          for (int nc = 0; nc < 4; ++nc)
            oacc[i][nc] = __builtin_amdgcn_mfma_f32_16x16x32_bf16(
                af[i], vf[nc], oacc[i][nc], 0, 0, 0);
      }
      __syncthreads();   // S reused by next iteration's QK (in-place buffer)
    }
  }

  // ---- uniform tail (half==1): k >= nt*64 -> all heads masked ->
  // attn = 1/16 exactly; add (1/16) * sum_{s>=s0u} V[h][e][s].
  float suf[4] = {0.f, 0.f, 0.f, 0.f};
  if (half == 1) {
    const int s0u = nt * 64;
    if (s0u < S_) {
      const int chunk = (S_ - s0u) >> 2;   // per-quad share, multiple of 8
#pragma unroll
      for (int nc = 0; nc < 4; ++nc) {
        const u16* vp = Vh + (size_t)(nc * 16 + l16) * S_ + s0u +
                        quad * chunk;
        float a = 0.f;
        for (int s = 0; s < chunk; s += 8) {
          ushort8 v8 = *(const ushort8*)(vp + s);
#pragma unroll
          for (int jj = 0; jj < 8; ++jj) a += b2f(v8[jj]);
        }
        suf[nc] = a;
      }
#pragma unroll
      for (int nc = 0; nc < 4; ++nc) {
        float a = suf[nc];
        a += __shfl_xor(a, 16);      // reduce across quad bits
        a += __shfl_xor(a, 32);
        suf[nc] = a * 0.0625f;       // * 1/16 (exact)
      }
    }
  }

  // ---- epilogue: accumulate partial into P (2 contributors/elem) ----
  float* Pb = P + ((size_t)(b * S_ + q0)) * D_ + h * E_;
#pragma unroll
  for (int i = 0; i < 2; ++i)
#pragma unroll
    for (int nc = 0; nc < 4; ++nc)
#pragma unroll
      for (int reg = 0; reg < 4; ++reg) {
        int qrow = i * 16 + quad * 4 + reg;
        int e    = nc * 16 + l16;
        unsafeAtomicAdd(&Pb[(size_t)qrow * D_ + e],
                        oacc[i][nc][reg] + suf[nc]);
      }
}

// ---------------------------------------------------------------------------
extern "C" void kernel_launch(void* const* d_in, const int* in_sizes, int n_in,
                              void* d_out, int out_size, void* d_ws,
                              size_t ws_size, hipStream_t stream)
{
  const float* X1 = (const float*)d_in[0];
  const float* X2 = (const float*)d_in[1];
  const float* Wq = (const float*)d_in[2];
  const float* bq = (const float*)d_in[3];
  const float* Wk = (const float*)d_in[4];
  const float* bk = (const float*)d_in[5];
  const float* Wv = (const float*)d_in[6];
  const float* bv = (const float*)d_in[7];
  const float* Wo = (const float*)d_in[8];
  const float* bo = (const float*)d_in[9];

  // Workspace (u16 units): X1b,X2b 8M each; Wt 1M x4; Qb,Kb,Vb,Vtb 8M each.
  // P (fp32 partial O, 32MB) aliases X1b+X2b (dead after QKV GEMMs).
  // AOb (bf16, 16MB) aliases Vb (dead after transpose_v). Total 88MB.
  u16* X1b = (u16*)d_ws;
  u16* X2b = X1b + (8u << 20);
  u16* WtQ = X2b + (8u << 20);
  u16* WtK = WtQ + (1u << 20);
  u16* WtV = WtK + (1u << 20);
  u16* WtO = WtV + (1u << 20);
  u16* Qb  = WtO + (1u << 20);
  u16* Kb  = Qb + (8u << 20);
  u16* Vb  = Kb + (8u << 20);
  u16* Vtb = Vb + (8u << 20);
  float* P = (float*)d_ws;   // 8192*1024 fp32 = 32MB = X1b+X2b region
  u16* AOb = Vb;             // alias

  cvt_bf16<<<4096, 256, 0, stream>>>(X1, X1b);
  cvt_bf16<<<4096, 256, 0, stream>>>(X2, X2b);

  dim3 tg(16, 16);
  trans_cvt_w<<<tg, 256, 0, stream>>>(Wq, WtQ);
  trans_cvt_w<<<tg, 256, 0, stream>>>(Wk, WtK);
  trans_cvt_w<<<tg, 256, 0, stream>>>(Wv, WtV);
  trans_cvt_w<<<tg, 256, 0, stream>>>(Wo, WtO);

  dim3 gg(64, 8);  // (M/128, N/128)
  gemm_bf16<<<gg, 256, 0, stream>>>(X1b, WtQ, bq, Qb, 8192, 1024, 1024, 0);
  gemm_bf16<<<gg, 256, 0, stream>>>(X2b, WtK, bk, Kb, 8192, 1024, 1024, 0);
  gemm_bf16<<<gg, 256, 0, stream>>>(X2b, WtV, bv, Vb, 8192, 1024, 1024, 0);

  transpose_v<<<dim3(16, 128), 256, 0, stream>>>(Vb, Vtb);

  // X1b/X2b dead now; zero P over their region, then accumulate partials.
  hipMemsetAsync(P, 0, (size_t)8192 * 1024 * 4, stream);

  attn_headsoftmax<<<dim3(512), 1024, 0, stream>>>(Qb, Kb, Vtb, P);

  cvt_bf16<<<4096, 256, 0, stream>>>(P, AOb);   // fp32 partial-sum -> bf16

  // Output fp32 (reference returns float32).
  gemm_bf16<<<gg, 256, 0, stream>>>(AOb, WtO, bo, d_out, 8192, 1024, 1024, 1);
}

// Round 9
// 413.741 us; speedup vs baseline: 1.1245x; 1.1245x over previous
//
#include <hip/hip_runtime.h>
#include <cstdint>

// ---------------------------------------------------------------------------
// MultiHeadAttention (B=8,S=1024,D=1024,H=16,E=64). Inputs fp32, output fp32.
// Quirks: scale = 1/sqrt(8) (d_k = batch quirk); tril + exact-zero -> -1e9
// (fp32, pre-round); softmax over HEADS axis (local per (b,q,k)).
//
// R16: consolidation. Attention = R14 byte-for-byte (172.4us measured; all
// structural levers exhausted: barrier count R13, VALU R14, work-halving
// R11/R15, occupancy R8/R10/R12/R15 -> latency-structure floor). Changes:
//  (1) gemm_bf16 __launch_bounds__(256,3): cap VGPR ~170 (m97's kernel is
//      164 naturally) to guarantee 3 blocks/CU; (256,1) allowed up to 512
//      VGPR -> possible occupancy starvation of the 4 GEMMs (~262us of the
//      434 total is non-attn; GEMM roofline at m97 efficiency is ~20us each).
//  (2) launch merges: 4x trans_cvt_w -> 1 (blockIdx.z selects matrix);
//      2x cvt_bf16 -> 1 (grid 8192, block range selects src). -5 launches.
//  attn reverted exactly -> total delta vs 434.2 isolates GEMM+launch wins.
// ---------------------------------------------------------------------------

typedef unsigned short u16;
typedef unsigned int   u32;
typedef __attribute__((ext_vector_type(8))) __bf16         bf16x8;
typedef __attribute__((ext_vector_type(8))) unsigned short ushort8;
typedef __attribute__((ext_vector_type(4))) float          f32x4;

#define S_ 1024
#define D_ 1024
#define H_ 16
#define E_ 64

__device__ __forceinline__ float b2f(u16 h) {
  union { u32 u; float f; } v; v.u = ((u32)h) << 16; return v.f;
}
__device__ __forceinline__ u16 f2b(float f) {      // round-to-nearest-even
  union { float f; u32 u; } v; v.f = f;
  u32 r = v.u + 0x7fffu + ((v.u >> 16) & 1u);
  return (u16)(r >> 16);
}

typedef const __attribute__((address_space(1))) u32 gu32;
typedef       __attribute__((address_space(3))) u32 lu32;

// 16B global->LDS direct load; LDS dest must be wave-uniform base + lane*16.
__device__ __forceinline__ void gload_lds16(const u16* g, u16* l) {
  __builtin_amdgcn_global_load_lds((gu32*)(uintptr_t)g, (lu32*)(uintptr_t)l,
                                   16, 0, 0);
}

// ---------------------------------------------------------------------------
// fp32 -> bf16 elementwise convert, two tensors in one launch (4096 blocks
// each; X1/X2 are 8M floats apiece).
// ---------------------------------------------------------------------------
__global__ __launch_bounds__(256, 1) void cvt2_bf16(
    const float* __restrict__ s0, const float* __restrict__ s1,
    u16* __restrict__ d0, u16* __restrict__ d1)
{
  const int blk = blockIdx.x;
  const float* src = (blk < 4096) ? s0 : s1;
  u16*         dst = (blk < 4096) ? d0 : d1;
  const size_t i = (size_t)(blk & 4095) * 256 + threadIdx.x;
  float4 a = ((const float4*)src)[2 * i];
  float4 b = ((const float4*)src)[2 * i + 1];
  ushort8 o;
  o[0] = f2b(a.x); o[1] = f2b(a.y); o[2] = f2b(a.z); o[3] = f2b(a.w);
  o[4] = f2b(b.x); o[5] = f2b(b.y); o[6] = f2b(b.z); o[7] = f2b(b.w);
  ((ushort8*)dst)[i] = o;
}

// ---------------------------------------------------------------------------
// Weight transpose+convert: W fp32 [K][N] -> Wt bf16 [N][K]. 64x64 tiles.
// All four weight matrices in one launch (blockIdx.z selects).
// ---------------------------------------------------------------------------
__global__ __launch_bounds__(256, 1) void trans_cvt_w4(
    const float* __restrict__ W0, const float* __restrict__ W1,
    const float* __restrict__ W2, const float* __restrict__ W3,
    u16* __restrict__ T0, u16* __restrict__ T1,
    u16* __restrict__ T2, u16* __restrict__ T3)
{
  __shared__ u16 t[64][72];
  const int z = blockIdx.z;
  const float* W = (z == 0) ? W0 : (z == 1) ? W1 : (z == 2) ? W2 : W3;
  u16*        Wt = (z == 0) ? T0 : (z == 1) ? T1 : (z == 2) ? T2 : T3;
  const int k0 = blockIdx.x * 64, n0 = blockIdx.y * 64;
  const int row = threadIdx.x >> 3;
  const int cs  = (threadIdx.x & 7) * 8;
#pragma unroll
  for (int p = 0; p < 2; ++p) {
    int r = row + p * 32;
    const float* Wp = W + (size_t)(k0 + r) * 1024 + n0 + cs;
    float4 a = *(const float4*)(Wp);
    float4 b = *(const float4*)(Wp + 4);
    u16* tp = &t[r][cs];
    tp[0] = f2b(a.x); tp[1] = f2b(a.y); tp[2] = f2b(a.z); tp[3] = f2b(a.w);
    tp[4] = f2b(b.x); tp[5] = f2b(b.y); tp[6] = f2b(b.z); tp[7] = f2b(b.w);
  }
  __syncthreads();
#pragma unroll
  for (int p = 0; p < 2; ++p) {
    int n = row + p * 32;
    ushort8 v;
#pragma unroll
    for (int i = 0; i < 8; ++i) v[i] = t[cs + i][n];
    *(ushort8*)(Wt + (size_t)(n0 + n) * 1024 + k0 + cs) = v;
  }
}

// ---------------------------------------------------------------------------
// bf16 MFMA GEMM: C[M][N] = A[M][K] @ Bt[N][K]^T + bias[N] (fp32 accum).
// 128x128 tile, BK=32, 256 threads / 4 waves. m97-style global_load_lds
// width-16 staging. out_f32: 1 -> fp32 stores, 0 -> bf16 stores.
// launch_bounds(256,3): VGPR cap ~170 (m97 = 164) -> guarantee 3 blocks/CU.
// ---------------------------------------------------------------------------
__global__ __launch_bounds__(256, 3) void gemm_bf16(
    const u16* __restrict__ A, const u16* __restrict__ Bt,
    const float* __restrict__ bias, void* __restrict__ Cv,
    int M, int N, int K, int out_f32)
{
  __shared__ u16 As[128 * 32];   // [m][k] row-major, 8KB
  __shared__ u16 Bs[128 * 32];   // [n][k] row-major, 8KB
  const int tid  = threadIdx.x;
  const int wave = tid >> 6;
  const int lane = tid & 63;
  const int quad = lane >> 4;
  const int l16  = lane & 15;
  const int m0   = (wave & 1) * 64;
  const int n0   = (wave >> 1) * 64;

  const u16* Ab = A  + (size_t)blockIdx.x * 128 * K;
  const u16* Bb = Bt + (size_t)blockIdx.y * 128 * K;

  f32x4 acc[4][4];
#pragma unroll
  for (int i = 0; i < 4; ++i)
#pragma unroll
    for (int j = 0; j < 4; ++j) acc[i][j] = (f32x4){0.f, 0.f, 0.f, 0.f};

  for (int kb = 0; kb < K; kb += 32) {
    __syncthreads();               // prior iter's LDS reads done
#pragma unroll
    for (int p = 0; p < 2; ++p) {  // 512 16B segs over 256 threads
      int seg = tid + p * 256;     // = (wave*64+p*256) + lane -> base+lane*16
      int row = seg >> 2, ks = seg & 3;
      gload_lds16(Ab + (size_t)row * K + kb + ks * 8, As + seg * 8);
      gload_lds16(Bb + (size_t)row * K + kb + ks * 8, Bs + seg * 8);
    }
    __builtin_amdgcn_s_waitcnt(0); // drain vmcnt before barrier
    __syncthreads();

    bf16x8 af[4], bfr[4];
#pragma unroll
    for (int i = 0; i < 4; ++i)    // A-frag: m=lane&15, k=quad*8+j
      af[i] = *(const bf16x8*)(As + (m0 + i * 16 + l16) * 32 + quad * 8);
#pragma unroll
    for (int j = 0; j < 4; ++j)    // B-frag: n=lane&15, k=quad*8+j
      bfr[j] = *(const bf16x8*)(Bs + (n0 + j * 16 + l16) * 32 + quad * 8);
#pragma unroll
    for (int i = 0; i < 4; ++i)
#pragma unroll
      for (int j = 0; j < 4; ++j)
        acc[i][j] = __builtin_amdgcn_mfma_f32_16x16x32_bf16(
            af[i], bfr[j], acc[i][j], 0, 0, 0);
  }

  float bv[4];
#pragma unroll
  for (int j = 0; j < 4; ++j)
    bv[j] = bias[(size_t)blockIdx.y * 128 + n0 + j * 16 + l16];

  if (out_f32) {
    float* C = (float*)Cv;
#pragma unroll
    for (int i = 0; i < 4; ++i) {
      int r = blockIdx.x * 128 + m0 + i * 16 + quad * 4;   // row=quad*4+reg
#pragma unroll
      for (int j = 0; j < 4; ++j) {
        int c = blockIdx.y * 128 + n0 + j * 16 + l16;      // col=lane&15
#pragma unroll
        for (int reg = 0; reg < 4; ++reg)
          C[(size_t)(r + reg) * N + c] = acc[i][j][reg] + bv[j];
      }
    }
  } else {
    u16* C = (u16*)Cv;
#pragma unroll
    for (int i = 0; i < 4; ++i) {
      int r = blockIdx.x * 128 + m0 + i * 16 + quad * 4;
#pragma unroll
      for (int j = 0; j < 4; ++j) {
        int c = blockIdx.y * 128 + n0 + j * 16 + l16;
#pragma unroll
        for (int reg = 0; reg < 4; ++reg)
          C[(size_t)(r + reg) * N + c] = f2b(acc[i][j][reg] + bv[j]);
      }
    }
  }
}

// ---------------------------------------------------------------------------
// V transpose (bf16): V[b][s][h*64+e] -> Vt[(b*16+h)*64+e][s]  (per-head E,S)
// ---------------------------------------------------------------------------
__global__ __launch_bounds__(256, 1) void transpose_v(
    const u16* __restrict__ V, u16* __restrict__ Vt)
{
  __shared__ u16 t[64][72];
  const int s0 = blockIdx.x * 64;
  const int bh = blockIdx.y;           // b*16 + h
  const int b = bh >> 4, h = bh & 15;
  const int row = threadIdx.x >> 3;
  const int cs  = (threadIdx.x & 7) * 8;
#pragma unroll
  for (int p = 0; p < 2; ++p) {
    int s = row + p * 32;
    *(ushort8*)(&t[s][cs]) = *(const ushort8*)(
        V + ((size_t)(b * S_ + s0 + s)) * D_ + h * E_ + cs);
  }
  __syncthreads();
#pragma unroll
  for (int p = 0; p < 2; ++p) {
    int e = row + p * 32;
    ushort8 v;
#pragma unroll
    for (int i = 0; i < 8; ++i) v[i] = t[cs + i][e];
    *(ushort8*)(Vt + ((size_t)(bh * E_ + e)) * S_ + s0 + cs) = v;
  }
}

// ---------------------------------------------------------------------------
// Fused attention, softmax over HEADS, bf16 MFMA.  R14 structure, verbatim
// (measured 172.4us, VGPR=64, the floor of this design family):
// R13 skeleton (32q/1024thr/16-warp, KVBLK=64, 16 compile-time iters).
// Softmax: thread=(q, 2 consec k) -> b32 LDS, conflict-free; masked points
// (k>q, head-independent) write 0x3D80 w/o exp; no max-sub (+sum==0 guard);
// tree sum. QK sub-tiles skipped when block-uniformly masked. 2 barriers.
// LDS: scf[16][32][72] + at[16][32][72] bf16 = 144KB (1 block/CU).
// ---------------------------------------------------------------------------
__global__ __launch_bounds__(1024, 4) void attn_headsoftmax(
    const u16* __restrict__ Qg,   // [B][S][D] bf16
    const u16* __restrict__ Kg,   // [B][S][D] bf16
    const u16* __restrict__ Vt,   // [B*H][E][S] bf16
    u16* __restrict__ AO)         // [B][S][D] bf16
{
  const int id   = blockIdx.x;         // 0..255; id&7 == b == XCD
  const int b    = id & 7;
  const int qt   = id >> 3;            // 0..31
  const int tid  = threadIdx.x;
  const int h    = tid >> 6;
  const int lane = tid & 63;
  const int quad = lane >> 4;
  const int l16  = lane & 15;
  const int q0   = qt * 32;

  __shared__ u16 scf[16][32][72];      // bf16 scores (72KB; 144B rows, 16B-al)
  __shared__ u16 at[16][32][72];       // bf16 attn   (72KB)

  const u16* Kh = Kg + (size_t)b * S_ * D_ + h * E_;
  const u16* Vh = Vt + ((size_t)(b * H_ + h) * E_) * S_;

  // 1/sqrt(8), correctly rounded fp32; s==0 <=> dot==0 under both forms.
  const float inv_rsq8 = 0.35355339059327373f;

  // ---- Q fragments (R7 verbatim) ----
  bf16x8 qf[2][2];
  {
    const u16* Qb = Qg + ((size_t)(b * S_ + q0)) * D_ + h * E_;
#pragma unroll
    for (int i = 0; i < 2; ++i)
#pragma unroll
      for (int c = 0; c < 2; ++c)
        qf[i][c] = *(const bf16x8*)(Qb + (size_t)(i * 16 + l16) * D_ +
                                    c * 32 + quad * 8);
  }

  f32x4 oacc[2][4];
#pragma unroll
  for (int i = 0; i < 2; ++i)
#pragma unroll
    for (int nc = 0; nc < 4; ++nc) oacc[i][nc] = (f32x4){0.f, 0.f, 0.f, 0.f};

  // softmax thread mapping: (q = tid>>5, k-chunk = (tid&31)*2)
  const int sm_q  = tid >> 5;
  const int sm_k  = (tid & 31) * 2;

  for (int kt = 0; kt < 16; ++kt) {
    const int k0 = kt * 64;
    // ---- QK^T: two 32-col sub-tiles; skip block-uniformly-masked ones ----
#pragma unroll
    for (int c2 = 0; c2 < 2; ++c2) {
      const int ks0 = k0 + c2 * 32;
      if (ks0 <= q0 + 31) {          // else fully masked: softmax writes 1/16
        const u16* Kb = Kh + (size_t)ks0 * D_;
        bf16x8 kf[2][2];
#pragma unroll
        for (int nc = 0; nc < 2; ++nc)
#pragma unroll
          for (int c = 0; c < 2; ++c)
            kf[nc][c] = *(const bf16x8*)(Kb + (size_t)(nc * 16 + l16) * D_ +
                                         c * 32 + quad * 8);
        f32x4 sacc[2][2];
#pragma unroll
        for (int i = 0; i < 2; ++i)
#pragma unroll
          for (int nc = 0; nc < 2; ++nc)
            sacc[i][nc] = (f32x4){0.f, 0.f, 0.f, 0.f};
#pragma unroll
        for (int c = 0; c < 2; ++c)
#pragma unroll
          for (int i = 0; i < 2; ++i)
#pragma unroll
            for (int nc = 0; nc < 2; ++nc)
              sacc[i][nc] = __builtin_amdgcn_mfma_f32_16x16x32_bf16(
                  qf[i][c], kf[nc][c], sacc[i][nc], 0, 0, 0);
#pragma unroll
        for (int i = 0; i < 2; ++i)
#pragma unroll
          for (int nc = 0; nc < 2; ++nc)
#pragma unroll
            for (int reg = 0; reg < 4; ++reg) {
              int qrow = i * 16 + quad * 4 + reg;  // C: row=quad*4+reg
              int kcol = nc * 16 + l16;            // C: col=lane&15
              float s = sacc[i][nc][reg] * inv_rsq8;
              if ((ks0 + kcol > q0 + qrow) || (s == 0.0f)) s = -1e9f;
              scf[h][qrow][c2 * 32 + kcol] = f2b(s);
            }
      }
    }
    __syncthreads();
    {  // ---- softmax across 16 heads; (q, 2 consec k) per thread ----
      const int qpos = q0 + sm_q;
      const int kpos = k0 + sm_k;
      int nU = qpos - kpos + 1;            // unmasked count in chunk [0..2]
      nU = nU < 0 ? 0 : (nU > 2 ? 2 : nU);
      if (nU == 0) {
        const u32 cc = 0x3D803D80u;        // bf16(1/16) x2
#pragma unroll
        for (int hh = 0; hh < 16; ++hh)
          *(u32*)&at[hh][sm_q][sm_k] = cc;
      } else {
        u32 v2[16];
#pragma unroll
        for (int hh = 0; hh < 16; ++hh)
          v2[hh] = *(const u32*)&scf[hh][sm_q][sm_k];
        u32 o2[16];
        {  // element 0 (always unmasked when nU>=1)
          float e0,e1,e2,e3,e4,e5,e6,e7,e8,e9,ea,eb,ec,ed,ee,ef;
          e0 = __expf(b2f((u16)(v2[0]  & 0xffffu)));
          e1 = __expf(b2f((u16)(v2[1]  & 0xffffu)));
          e2 = __expf(b2f((u16)(v2[2]  & 0xffffu)));
          e3 = __expf(b2f((u16)(v2[3]  & 0xffffu)));
          e4 = __expf(b2f((u16)(v2[4]  & 0xffffu)));
          e5 = __expf(b2f((u16)(v2[5]  & 0xffffu)));
          e6 = __expf(b2f((u16)(v2[6]  & 0xffffu)));
          e7 = __expf(b2f((u16)(v2[7]  & 0xffffu)));
          e8 = __expf(b2f((u16)(v2[8]  & 0xffffu)));
          e9 = __expf(b2f((u16)(v2[9]  & 0xffffu)));
          ea = __expf(b2f((u16)(v2[10] & 0xffffu)));
          eb = __expf(b2f((u16)(v2[11] & 0xffffu)));
          ec = __expf(b2f((u16)(v2[12] & 0xffffu)));
          ed = __expf(b2f((u16)(v2[13] & 0xffffu)));
          ee = __expf(b2f((u16)(v2[14] & 0xffffu)));
          ef = __expf(b2f((u16)(v2[15] & 0xffffu)));
          float sum = (((e0+e1)+(e2+e3))+((e4+e5)+(e6+e7)))
                    + (((e8+e9)+(ea+eb))+((ec+ed)+(ee+ef)));
          float inv = 1.0f / sum;
          bool z = (sum == 0.0f);          // all-quirk guard -> uniform 1/16
          o2[0]  = z ? 0x3D80u : (u32)f2b(e0 * inv);
          o2[1]  = z ? 0x3D80u : (u32)f2b(e1 * inv);
          o2[2]  = z ? 0x3D80u : (u32)f2b(e2 * inv);
          o2[3]  = z ? 0x3D80u : (u32)f2b(e3 * inv);
          o2[4]  = z ? 0x3D80u : (u32)f2b(e4 * inv);
          o2[5]  = z ? 0x3D80u : (u32)f2b(e5 * inv);
          o2[6]  = z ? 0x3D80u : (u32)f2b(e6 * inv);
          o2[7]  = z ? 0x3D80u : (u32)f2b(e7 * inv);
          o2[8]  = z ? 0x3D80u : (u32)f2b(e8 * inv);
          o2[9]  = z ? 0x3D80u : (u32)f2b(e9 * inv);
          o2[10] = z ? 0x3D80u : (u32)f2b(ea * inv);
          o2[11] = z ? 0x3D80u : (u32)f2b(eb * inv);
          o2[12] = z ? 0x3D80u : (u32)f2b(ec * inv);
          o2[13] = z ? 0x3D80u : (u32)f2b(ed * inv);
          o2[14] = z ? 0x3D80u : (u32)f2b(ee * inv);
          o2[15] = z ? 0x3D80u : (u32)f2b(ef * inv);
        }
        if (nU == 2) {  // element 1 real
          float e0,e1,e2,e3,e4,e5,e6,e7,e8,e9,ea,eb,ec,ed,ee,ef;
          e0 = __expf(b2f((u16)(v2[0]  >> 16)));
          e1 = __expf(b2f((u16)(v2[1]  >> 16)));
          e2 = __expf(b2f((u16)(v2[2]  >> 16)));
          e3 = __expf(b2f((u16)(v2[3]  >> 16)));
          e4 = __expf(b2f((u16)(v2[4]  >> 16)));
          e5 = __expf(b2f((u16)(v2[5]  >> 16)));
          e6 = __expf(b2f((u16)(v2[6]  >> 16)));
          e7 = __expf(b2f((u16)(v2[7]  >> 16)));
          e8 = __expf(b2f((u16)(v2[8]  >> 16)));
          e9 = __expf(b2f((u16)(v2[9]  >> 16)));
          ea = __expf(b2f((u16)(v2[10] >> 16)));
          eb = __expf(b2f((u16)(v2[11] >> 16)));
          ec = __expf(b2f((u16)(v2[12] >> 16)));
          ed = __expf(b2f((u16)(v2[13] >> 16)));
          ee = __expf(b2f((u16)(v2[14] >> 16)));
          ef = __expf(b2f((u16)(v2[15] >> 16)));
          float sum = (((e0+e1)+(e2+e3))+((e4+e5)+(e6+e7)))
                    + (((e8+e9)+(ea+eb))+((ec+ed)+(ee+ef)));
          float inv = 1.0f / sum;
          bool z = (sum == 0.0f);
          o2[0]  |= ((u32)(z ? 0x3D80u : f2b(e0 * inv))) << 16;
          o2[1]  |= ((u32)(z ? 0x3D80u : f2b(e1 * inv))) << 16;
          o2[2]  |= ((u32)(z ? 0x3D80u : f2b(e2 * inv))) << 16;
          o2[3]  |= ((u32)(z ? 0x3D80u : f2b(e3 * inv))) << 16;
          o2[4]  |= ((u32)(z ? 0x3D80u : f2b(e4 * inv))) << 16;
          o2[5]  |= ((u32)(z ? 0x3D80u : f2b(e5 * inv))) << 16;
          o2[6]  |= ((u32)(z ? 0x3D80u : f2b(e6 * inv))) << 16;
          o2[7]  |= ((u32)(z ? 0x3D80u : f2b(e7 * inv))) << 16;
          o2[8]  |= ((u32)(z ? 0x3D80u : f2b(e8 * inv))) << 16;
          o2[9]  |= ((u32)(z ? 0x3D80u : f2b(e9 * inv))) << 16;
          o2[10] |= ((u32)(z ? 0x3D80u : f2b(ea * inv))) << 16;
          o2[11] |= ((u32)(z ? 0x3D80u : f2b(eb * inv))) << 16;
          o2[12] |= ((u32)(z ? 0x3D80u : f2b(ec * inv))) << 16;
          o2[13] |= ((u32)(z ? 0x3D80u : f2b(ed * inv))) << 16;
          o2[14] |= ((u32)(z ? 0x3D80u : f2b(ee * inv))) << 16;
          o2[15] |= ((u32)(z ? 0x3D80u : f2b(ef * inv))) << 16;
        } else {        // element 1 masked -> 1/16
#pragma unroll
          for (int hh = 0; hh < 16; ++hh) o2[hh] |= 0x3D800000u;
        }
#pragma unroll
        for (int hh = 0; hh < 16; ++hh)
          *(u32*)&at[hh][sm_q][sm_k] = o2[hh];
      }
    }
    __syncthreads();
    // ---- PV: two 32-col sub-tiles (always full: masked attn == 1/16) ----
#pragma unroll
    for (int c2 = 0; c2 < 2; ++c2) {
      bf16x8 af[2];
#pragma unroll
      for (int i = 0; i < 2; ++i)    // A: m=q (lane&15), k=s (quad*8+jj)
        af[i] = *(const bf16x8*)(&at[h][i * 16 + l16][c2 * 32 + quad * 8]);
      const u16* Vb = Vh + k0 + c2 * 32;
      bf16x8 vf[4];
#pragma unroll
      for (int nc = 0; nc < 4; ++nc) // B: n=e (lane&15), k=s (quad*8+jj)
        vf[nc] = *(const bf16x8*)(Vb + (size_t)(nc * 16 + l16) * S_ +
                                  quad * 8);
#pragma unroll
      for (int i = 0; i < 2; ++i)
#pragma unroll
        for (int nc = 0; nc < 4; ++nc)
          oacc[i][nc] = __builtin_amdgcn_mfma_f32_16x16x32_bf16(
              af[i], vf[nc], oacc[i][nc], 0, 0, 0);
    }
    // no barrier: next QK writes scf (last read pre-2nd-barrier); `at`
    // reuse is ordered by next iteration's post-QK barrier.
  }

  u16* Ob = AO + ((size_t)(b * S_ + q0)) * D_ + h * E_;
#pragma unroll
  for (int i = 0; i < 2; ++i)
#pragma unroll
    for (int nc = 0; nc < 4; ++nc)
#pragma unroll
      for (int reg = 0; reg < 4; ++reg) {
        int qrow = i * 16 + quad * 4 + reg;
        int e    = nc * 16 + l16;
        Ob[(size_t)qrow * D_ + e] = f2b(oacc[i][nc][reg]);
      }
}

// ---------------------------------------------------------------------------
extern "C" void kernel_launch(void* const* d_in, const int* in_sizes, int n_in,
                              void* d_out, int out_size, void* d_ws,
                              size_t ws_size, hipStream_t stream)
{
  const float* X1 = (const float*)d_in[0];
  const float* X2 = (const float*)d_in[1];
  const float* Wq = (const float*)d_in[2];
  const float* bq = (const float*)d_in[3];
  const float* Wk = (const float*)d_in[4];
  const float* bk = (const float*)d_in[5];
  const float* Wv = (const float*)d_in[6];
  const float* bv = (const float*)d_in[7];
  const float* Wo = (const float*)d_in[8];
  const float* bo = (const float*)d_in[9];

  // Workspace (u16 units): X1b,X2b 8M; Wt 1M x4; Qb,Kb,Vb,Vtb 8M. AO aliases
  // Vb (dead after transpose_v). Total 44M u16 = 88MB.
  u16* X1b = (u16*)d_ws;
  u16* X2b = X1b + (8u << 20);
  u16* WtQ = X2b + (8u << 20);
  u16* WtK = WtQ + (1u << 20);
  u16* WtV = WtK + (1u << 20);
  u16* WtO = WtV + (1u << 20);
  u16* Qb  = WtO + (1u << 20);
  u16* Kb  = Qb + (8u << 20);
  u16* Vb  = Kb + (8u << 20);
  u16* Vtb = Vb + (8u << 20);
  u16* AOb = Vb;  // alias

  cvt2_bf16<<<8192, 256, 0, stream>>>(X1, X2, X1b, X2b);

  trans_cvt_w4<<<dim3(16, 16, 4), 256, 0, stream>>>(
      Wq, Wk, Wv, Wo, WtQ, WtK, WtV, WtO);

  dim3 gg(64, 8);  // (M/128, N/128)
  gemm_bf16<<<gg, 256, 0, stream>>>(X1b, WtQ, bq, Qb, 8192, 1024, 1024, 0);
  gemm_bf16<<<gg, 256, 0, stream>>>(X2b, WtK, bk, Kb, 8192, 1024, 1024, 0);
  gemm_bf16<<<gg, 256, 0, stream>>>(X2b, WtV, bv, Vb, 8192, 1024, 1024, 0);

  transpose_v<<<dim3(16, 128), 256, 0, stream>>>(Vb, Vtb);

  attn_headsoftmax<<<dim3(256), 1024, 0, stream>>>(Qb, Kb, Vtb, AOb);

  // Output fp32 (reference returns float32).
  gemm_bf16<<<gg, 256, 0, stream>>>(AOb, WtO, bo, d_out, 8192, 1024, 1024, 1);
}